// Round 1
// baseline (486.349 us; speedup 1.0000x reference)
//
#include <hip/hip_runtime.h>

#define HDIM 128

// C[M,128] = Z[M,128] @ W[128,128] (+ bias broadcast over rows)
// Block: 256 threads, 32 rows x 128 cols per block, 4x4 register tile/thread.
__global__ __launch_bounds__(256) void node_gemm(
    const float* __restrict__ Z, const float* __restrict__ W,
    const float* __restrict__ bias, float* __restrict__ C, int M)
{
    __shared__ float zT[128][36];   // transposed Z tile, +4 pad keeps 16B align
    __shared__ float ws[64][128];   // W k-chunk

    const int t    = threadIdx.x;
    const int row0 = blockIdx.x * 32;

    // ---- load + transpose Z tile: rows row0..row0+31, all 128 k ----
    {
        const int r  = t >> 3;           // 0..31
        const int k0 = (t & 7) << 4;     // 0,16,...,112
        int rg = row0 + r;
        if (rg >= M) rg = M - 1;         // clamp (M=100000 is 32-divisible; insurance)
        const float4* Zv = reinterpret_cast<const float4*>(Z + (size_t)rg * HDIM + k0);
        float4 v0 = Zv[0], v1 = Zv[1], v2 = Zv[2], v3 = Zv[3];
        float vv[16] = {v0.x,v0.y,v0.z,v0.w, v1.x,v1.y,v1.z,v1.w,
                        v2.x,v2.y,v2.z,v2.w, v3.x,v3.y,v3.z,v3.w};
        #pragma unroll
        for (int i = 0; i < 16; ++i) zT[k0 + i][r] = vv[i];
    }

    const int tx = t & 31;   // col group: cols 4*tx..4*tx+3
    const int ty = t >> 5;   // row group: rows ty*4..ty*4+3

    float acc[4][4];
    if (bias) {
        const float4 bv = *reinterpret_cast<const float4*>(bias + tx * 4);
        #pragma unroll
        for (int r = 0; r < 4; ++r) {
            acc[r][0] = bv.x; acc[r][1] = bv.y; acc[r][2] = bv.z; acc[r][3] = bv.w;
        }
    } else {
        #pragma unroll
        for (int r = 0; r < 4; ++r)
            #pragma unroll
            for (int c = 0; c < 4; ++c) acc[r][c] = 0.f;
    }

    for (int kk = 0; kk < 128; kk += 64) {
        __syncthreads();  // zT ready (iter0) / ws fully consumed (iter1)
        {   // stage W[kk..kk+64) -> ws : 8192 floats = 2048 float4, 8/thread
            const float4* Wv = reinterpret_cast<const float4*>(W + (size_t)kk * HDIM);
            float4* Sv = reinterpret_cast<float4*>(&ws[0][0]);
            #pragma unroll
            for (int i = 0; i < 8; ++i) Sv[t + 256 * i] = Wv[t + 256 * i];
        }
        __syncthreads();

        #pragma unroll 8
        for (int k = 0; k < 64; ++k) {
            const float4 zv = *reinterpret_cast<const float4*>(&zT[kk + k][ty * 4]);
            const float4 wv = *reinterpret_cast<const float4*>(&ws[k][tx * 4]);
            acc[0][0] += zv.x * wv.x; acc[0][1] += zv.x * wv.y;
            acc[0][2] += zv.x * wv.z; acc[0][3] += zv.x * wv.w;
            acc[1][0] += zv.y * wv.x; acc[1][1] += zv.y * wv.y;
            acc[1][2] += zv.y * wv.z; acc[1][3] += zv.y * wv.w;
            acc[2][0] += zv.z * wv.x; acc[2][1] += zv.z * wv.y;
            acc[2][2] += zv.z * wv.z; acc[2][3] += zv.z * wv.w;
            acc[3][0] += zv.w * wv.x; acc[3][1] += zv.w * wv.y;
            acc[3][2] += zv.w * wv.z; acc[3][3] += zv.w * wv.w;
        }
    }

    #pragma unroll
    for (int r = 0; r < 4; ++r) {
        const int row = row0 + ty * 4 + r;
        if (row < M) {
            float4 o = make_float4(acc[r][0], acc[r][1], acc[r][2], acc[r][3]);
            *reinterpret_cast<float4*>(C + (size_t)row * HDIM + tx * 4) = o;
        }
    }
}

// out[e] = relu(A[row[e]] + B[col[e]]) . W2 + b2   (b1 pre-folded into B)
// One 32-lane half-wave per edge; lane handles 4 features (float4 = 16B/lane).
__global__ __launch_bounds__(256) void edge_decode(
    const float* __restrict__ A, const float* __restrict__ Bm,
    const int* __restrict__ idx,   // [2*E] flat: rows then cols
    const float* __restrict__ W2, const float* __restrict__ b2,
    float* __restrict__ out, int E)
{
    const int t    = threadIdx.x;
    const int lane = t & 63;
    const int sub  = lane & 31;          // lane within half-wave
    const int grp  = t >> 5;             // half-wave id in block: 0..7

    const float4 w2v = *reinterpret_cast<const float4*>(W2 + sub * 4);
    const float  b2s = b2[0];

    const int stride = gridDim.x * 8;
    for (int e = blockIdx.x * 8 + grp; e < E; e += stride) {
        const int r = idx[e];
        const int c = idx[E + e];
        const float4 a = *reinterpret_cast<const float4*>(A  + (size_t)r * HDIM + sub * 4);
        const float4 b = *reinterpret_cast<const float4*>(Bm + (size_t)c * HDIM + sub * 4);
        float s = fmaxf(a.x + b.x, 0.f) * w2v.x
                + fmaxf(a.y + b.y, 0.f) * w2v.y
                + fmaxf(a.z + b.z, 0.f) * w2v.z
                + fmaxf(a.w + b.w, 0.f) * w2v.w;
        s += __shfl_xor(s, 1);
        s += __shfl_xor(s, 2);
        s += __shfl_xor(s, 4);
        s += __shfl_xor(s, 8);
        s += __shfl_xor(s, 16);
        if (sub == 0) out[e] = s + b2s;
    }
}

extern "C" void kernel_launch(void* const* d_in, const int* in_sizes, int n_in,
                              void* d_out, int out_size, void* d_ws, size_t ws_size,
                              hipStream_t stream)
{
    const float* z_src = (const float*)d_in[0];
    const float* z_dst = (const float*)d_in[1];
    const int*   eidx  = (const int*)d_in[2];
    const float* W1    = (const float*)d_in[3];
    const float* b1    = (const float*)d_in[4];
    const float* W2    = (const float*)d_in[5];
    const float* b2    = (const float*)d_in[6];
    float*       outp  = (float*)d_out;

    const int Nn = in_sizes[0] / HDIM;    // 100000
    const int E  = in_sizes[2] / 2;       // 2000000

    float* Abuf = (float*)d_ws;
    float* Bbuf = Abuf + (size_t)Nn * HDIM;

    const int gblocks = (Nn + 31) / 32;
    // A = z_src @ W1[:H]            (no bias)
    node_gemm<<<gblocks, 256, 0, stream>>>(z_src, W1,              nullptr, Abuf, Nn);
    // B = z_dst @ W1[H:] + b1       (fold b1)
    node_gemm<<<gblocks, 256, 0, stream>>>(z_dst, W1 + HDIM * HDIM, b1,     Bbuf, Nn);

    edge_decode<<<4096, 256, 0, stream>>>(Abuf, Bbuf, eidx, W2, b2, outp, E);
}

// Round 2
// 339.211 us; speedup vs baseline: 1.4338x; 1.4338x over previous
//
#include <hip/hip_runtime.h>

#define HDIM 128

__device__ __forceinline__ unsigned short f2bf_rne(float f) {
    unsigned int u = __float_as_uint(f);
    u += 0x7fffu + ((u >> 16) & 1u);   // round-to-nearest-even
    return (unsigned short)(u >> 16);
}

// C_bf16[M,128] = Z[M,128] @ W[128,128] (+ bias). Two problems in one grid:
// blocks [0,gb) do Z=Zs,W=W1a,no-bias -> Abuf; blocks [gb,2gb) do Zd,W1b,+b1 -> Bbuf.
__global__ __launch_bounds__(256) void node_gemm_dual(
    const float* __restrict__ Zs, const float* __restrict__ Zd,
    const float* __restrict__ W1, const float* __restrict__ b1,
    unsigned short* __restrict__ Abuf, unsigned short* __restrict__ Bbuf,
    int M, int gb)
{
    __shared__ float zT[128][36];   // transposed Z tile (pad keeps 16B align: 36*4=144)
    __shared__ float ws[64][128];   // W k-chunk

    const bool second = (blockIdx.x >= gb);
    const float* __restrict__ Z    = second ? Zd : Zs;
    const float* __restrict__ W    = second ? (W1 + HDIM * HDIM) : W1;
    unsigned short* __restrict__ C = second ? Bbuf : Abuf;
    const int bx   = second ? (blockIdx.x - gb) : blockIdx.x;
    const int t    = threadIdx.x;
    const int row0 = bx * 32;

    // ---- load + transpose Z tile ----
    {
        const int r  = t >> 3;           // 0..31
        const int k0 = (t & 7) << 4;     // 0,16,...,112
        int rg = row0 + r;
        if (rg >= M) rg = M - 1;
        const float4* Zv = reinterpret_cast<const float4*>(Z + (size_t)rg * HDIM + k0);
        float4 v0 = Zv[0], v1 = Zv[1], v2 = Zv[2], v3 = Zv[3];
        float vv[16] = {v0.x,v0.y,v0.z,v0.w, v1.x,v1.y,v1.z,v1.w,
                        v2.x,v2.y,v2.z,v2.w, v3.x,v3.y,v3.z,v3.w};
        #pragma unroll
        for (int i = 0; i < 16; ++i) zT[k0 + i][r] = vv[i];
    }

    const int tx = t & 31;   // cols 4*tx..4*tx+3
    const int ty = t >> 5;   // rows ty*4..ty*4+3

    float acc[4][4];
    if (second) {
        const float4 bv = *reinterpret_cast<const float4*>(b1 + tx * 4);
        #pragma unroll
        for (int r = 0; r < 4; ++r) {
            acc[r][0] = bv.x; acc[r][1] = bv.y; acc[r][2] = bv.z; acc[r][3] = bv.w;
        }
    } else {
        #pragma unroll
        for (int r = 0; r < 4; ++r)
            #pragma unroll
            for (int c = 0; c < 4; ++c) acc[r][c] = 0.f;
    }

    for (int kk = 0; kk < 128; kk += 64) {
        __syncthreads();
        {   // stage W[kk..kk+64) -> ws
            const float4* Wv = reinterpret_cast<const float4*>(W + (size_t)kk * HDIM);
            float4* Sv = reinterpret_cast<float4*>(&ws[0][0]);
            #pragma unroll
            for (int i = 0; i < 8; ++i) Sv[t + 256 * i] = Wv[t + 256 * i];
        }
        __syncthreads();

        #pragma unroll 8
        for (int k = 0; k < 64; ++k) {
            const float4 zv = *reinterpret_cast<const float4*>(&zT[kk + k][ty * 4]);
            const float4 wv = *reinterpret_cast<const float4*>(&ws[k][tx * 4]);
            acc[0][0] += zv.x * wv.x; acc[0][1] += zv.x * wv.y;
            acc[0][2] += zv.x * wv.z; acc[0][3] += zv.x * wv.w;
            acc[1][0] += zv.y * wv.x; acc[1][1] += zv.y * wv.y;
            acc[1][2] += zv.y * wv.z; acc[1][3] += zv.y * wv.w;
            acc[2][0] += zv.z * wv.x; acc[2][1] += zv.z * wv.y;
            acc[2][2] += zv.z * wv.z; acc[2][3] += zv.z * wv.w;
            acc[3][0] += zv.w * wv.x; acc[3][1] += zv.w * wv.y;
            acc[3][2] += zv.w * wv.z; acc[3][3] += zv.w * wv.w;
        }
    }

    #pragma unroll
    for (int r = 0; r < 4; ++r) {
        const int row = row0 + ty * 4 + r;
        if (row < M) {
            ushort4 o;
            o.x = f2bf_rne(acc[r][0]); o.y = f2bf_rne(acc[r][1]);
            o.z = f2bf_rne(acc[r][2]); o.w = f2bf_rne(acc[r][3]);
            *reinterpret_cast<ushort4*>(C + (size_t)row * HDIM + tx * 4) = o;
        }
    }
}

// out[e] = relu(A[row[e]] + B[col[e]]) . W2 + b2  with A,B in bf16 (b1 folded into B).
// 16 lanes per edge; lane handles 8 features (16 B bf16 load/operand).
__global__ __launch_bounds__(256) void edge_decode_bf16(
    const unsigned short* __restrict__ A, const unsigned short* __restrict__ Bm,
    const int* __restrict__ idx,   // [2*E]: rows then cols
    const float* __restrict__ W2, const float* __restrict__ b2,
    float* __restrict__ out, int E)
{
    const int t   = threadIdx.x;
    const int sub = t & 15;          // lane in 16-lane group
    const int grp = t >> 4;          // group id in block: 0..15

    float w2r[8];
    #pragma unroll
    for (int i = 0; i < 8; ++i) w2r[i] = W2[sub * 8 + i];
    const float b2s = b2[0];

    const int stride = gridDim.x * 16;
    for (int e = blockIdx.x * 16 + grp; e < E; e += stride) {
        const int r = idx[e];
        const int c = idx[E + e];
        const uint4 av = *reinterpret_cast<const uint4*>(A  + (size_t)r * HDIM + sub * 8);
        const uint4 bv = *reinterpret_cast<const uint4*>(Bm + (size_t)c * HDIM + sub * 8);

        float s = 0.f;
        #pragma unroll
        for (int i = 0; i < 4; ++i) {
            const unsigned int ua = (&av.x)[i];
            const unsigned int ub = (&bv.x)[i];
            const float a0 = __uint_as_float(ua << 16);
            const float a1 = __uint_as_float(ua & 0xffff0000u);
            const float b0 = __uint_as_float(ub << 16);
            const float b1v = __uint_as_float(ub & 0xffff0000u);
            s += fmaxf(a0 + b0,  0.f) * w2r[2 * i];
            s += fmaxf(a1 + b1v, 0.f) * w2r[2 * i + 1];
        }
        s += __shfl_xor(s, 1);
        s += __shfl_xor(s, 2);
        s += __shfl_xor(s, 4);
        s += __shfl_xor(s, 8);
        if (sub == 0) out[e] = s + b2s;
    }
}

extern "C" void kernel_launch(void* const* d_in, const int* in_sizes, int n_in,
                              void* d_out, int out_size, void* d_ws, size_t ws_size,
                              hipStream_t stream)
{
    const float* z_src = (const float*)d_in[0];
    const float* z_dst = (const float*)d_in[1];
    const int*   eidx  = (const int*)d_in[2];
    const float* W1    = (const float*)d_in[3];
    const float* b1    = (const float*)d_in[4];
    const float* W2    = (const float*)d_in[5];
    const float* b2    = (const float*)d_in[6];
    float*       outp  = (float*)d_out;

    const int Nn = in_sizes[0] / HDIM;    // 100000
    const int E  = in_sizes[2] / 2;       // 2000000

    unsigned short* Abuf = (unsigned short*)d_ws;
    unsigned short* Bbuf = Abuf + (size_t)Nn * HDIM;

    const int gb = (Nn + 31) / 32;
    node_gemm_dual<<<2 * gb, 256, 0, stream>>>(z_src, z_dst, W1, b1, Abuf, Bbuf, Nn, gb);
    edge_decode_bf16<<<8192, 256, 0, stream>>>(Abuf, Bbuf, eidx, W2, b2, outp, E);
}

// Round 3
// 296.256 us; speedup vs baseline: 1.6417x; 1.1450x over previous
//
#include <hip/hip_runtime.h>

#define HDIM 128

typedef __bf16 bf16_t;
typedef bf16_t bf16x8 __attribute__((ext_vector_type(8)));
typedef float  f32x4  __attribute__((ext_vector_type(4)));

__device__ __forceinline__ unsigned short f2bf_rne(float f) {
    unsigned int u = __float_as_uint(f);
    u += 0x7fffu + ((u >> 16) & 1u);   // round-to-nearest-even
    return (unsigned short)(u >> 16);
}
__device__ __forceinline__ unsigned int pk_bf2(float a, float b) {
    return (unsigned int)f2bf_rne(a) | ((unsigned int)f2bf_rne(b) << 16);
}

// W1 [2*128 k][128 n] fp32 -> Wt [2][n=128][k=128] bf16 (n-major, k-contiguous)
__global__ __launch_bounds__(256) void convert_w1(
    const float* __restrict__ W1, unsigned short* __restrict__ Wt)
{
    const int o = blockIdx.x * 256 + threadIdx.x;     // 0..32767
    const int g = o >> 14, rem = o & 16383, n = rem >> 7, k = rem & 127;
    Wt[o] = f2bf_rne(W1[g * 16384 + k * 128 + n]);
}

// C_bf16[M,128] = bf16(Z[M,128]) @ bf16(W[128,128]) (+ b1 if second problem)
// 64 rows x 128 cols per block; full K=128 staged in LDS; MFMA 16x16x32 bf16.
#define ZP 136   // LDS pitch in shorts: 272 B (16B-aligned, bank-balanced)
__global__ __launch_bounds__(256) void node_gemm_mfma(
    const float* __restrict__ Zs, const float* __restrict__ Zd,
    const unsigned short* __restrict__ Wt, const float* __restrict__ b1,
    unsigned short* __restrict__ Abuf, unsigned short* __restrict__ Bbuf,
    int M, int gb)
{
    __shared__ unsigned short zs[64 * ZP];    // Z tile, bf16, row-major k-contig
    __shared__ unsigned short wsm[128 * ZP];  // W, bf16, n-major k-contig

    const bool second = (blockIdx.x >= gb);
    const float* __restrict__ Z          = second ? Zd : Zs;
    const unsigned short* __restrict__ W = Wt + (second ? 128 * 128 : 0);
    unsigned short* __restrict__ C       = second ? Bbuf : Abuf;
    const int bx   = second ? (blockIdx.x - gb) : blockIdx.x;
    const int row0 = bx * 64;
    const int t    = threadIdx.x;

    // ---- stage Z (64x128 fp32 -> bf16 LDS), fully-coalesced float4 loads ----
    #pragma unroll
    for (int j = 0; j < 8; ++j) {
        const int u   = t + 256 * j;       // 0..2047 float4-chunks
        const int row = u >> 5;            // 0..63
        const int c4  = u & 31;            // float4 index in row
        int rg = row0 + row; if (rg >= M) rg = M - 1;
        const float4 v = *reinterpret_cast<const float4*>(Z + (size_t)rg * HDIM + c4 * 4);
        uint2 p; p.x = pk_bf2(v.x, v.y); p.y = pk_bf2(v.z, v.w);
        *reinterpret_cast<uint2*>(zs + row * ZP + c4 * 4) = p;
    }
    // ---- stage W (128x128 bf16), contiguous 16B loads/stores ----
    #pragma unroll
    for (int j = 0; j < 8; ++j) {
        const int u  = t + 256 * j;        // 0..2047 uint4-chunks
        const int n  = u >> 4;             // 0..127
        const int k8 = u & 15;             // 8-short chunk in row
        const uint4 v = *reinterpret_cast<const uint4*>(W + n * 128 + k8 * 8);
        *reinterpret_cast<uint4*>(wsm + n * ZP + k8 * 8) = v;
    }
    __syncthreads();

    const int lane = t & 63;
    const int wave = t >> 6;
    const int m    = lane & 15;
    const int quad = lane >> 4;
    const int rw   = wave & 1;    // row half: 32 rows
    const int cw   = wave >> 1;   // col half: 64 cols

    const int aoff0 = (rw * 32 +  0 + m) * ZP + quad * 8;
    const int aoff1 = (rw * 32 + 16 + m) * ZP + quad * 8;
    const int boff  = (cw * 64 + m) * ZP + quad * 8;

    f32x4 acc[2][4] = {};
    #pragma unroll
    for (int ks = 0; ks < 4; ++ks) {
        const int ko = ks * 32;
        const bf16x8 a0 = *reinterpret_cast<const bf16x8*>(zs + aoff0 + ko);
        const bf16x8 a1 = *reinterpret_cast<const bf16x8*>(zs + aoff1 + ko);
        #pragma unroll
        for (int ct = 0; ct < 4; ++ct) {
            const bf16x8 bb = *reinterpret_cast<const bf16x8*>(wsm + boff + ct * 16 * ZP + ko);
            acc[0][ct] = __builtin_amdgcn_mfma_f32_16x16x32_bf16(a0, bb, acc[0][ct], 0, 0, 0);
            acc[1][ct] = __builtin_amdgcn_mfma_f32_16x16x32_bf16(a1, bb, acc[1][ct], 0, 0, 0);
        }
    }

    // ---- epilogue: +bias (second problem), fp32 -> bf16, store ----
    const int colbase = cw * 64 + m;
    #pragma unroll
    for (int ct = 0; ct < 4; ++ct) {
        const int col = colbase + ct * 16;
        const float bv = second ? b1[col] : 0.f;
        #pragma unroll
        for (int rt = 0; rt < 2; ++rt) {
            #pragma unroll
            for (int i = 0; i < 4; ++i) {
                const int gr = row0 + rw * 32 + rt * 16 + quad * 4 + i;
                if (gr < M)
                    C[(size_t)gr * HDIM + col] = f2bf_rne(acc[rt][ct][i] + bv);
            }
        }
    }
}

// out[e] = relu(A[row[e]] + B[col[e]]) . W2 + b2, A/B bf16 (b1 folded into B).
// 16 lanes/edge, 2 edges in flight per group for MLP.
__global__ __launch_bounds__(256) void edge_decode_bf16(
    const unsigned short* __restrict__ A, const unsigned short* __restrict__ Bm,
    const int* __restrict__ idx,   // [2*E]: rows then cols
    const float* __restrict__ W2, const float* __restrict__ b2,
    float* __restrict__ out, int E)
{
    const int t   = threadIdx.x;
    const int sub = t & 15;
    const int grp = t >> 4;

    float w2r[8];
    #pragma unroll
    for (int i = 0; i < 8; ++i) w2r[i] = W2[sub * 8 + i];
    const float b2s = b2[0];

    const int G = gridDim.x * 16;
    for (int e0 = blockIdx.x * 16 + grp; e0 < E; e0 += 2 * G) {
        const int  e1 = e0 + G;
        const bool h1 = (e1 < E);
        const int r0 = idx[e0];
        const int c0 = idx[E + e0];
        const int r1 = h1 ? idx[e1]     : r0;
        const int c1 = h1 ? idx[E + e1] : c0;

        const uint4 a0 = *reinterpret_cast<const uint4*>(A  + (size_t)r0 * HDIM + sub * 8);
        const uint4 b0 = *reinterpret_cast<const uint4*>(Bm + (size_t)c0 * HDIM + sub * 8);
        const uint4 a1 = *reinterpret_cast<const uint4*>(A  + (size_t)r1 * HDIM + sub * 8);
        const uint4 b1v = *reinterpret_cast<const uint4*>(Bm + (size_t)c1 * HDIM + sub * 8);

        float s0 = 0.f, s1 = 0.f;
        #pragma unroll
        for (int i = 0; i < 4; ++i) {
            unsigned int ua = (&a0.x)[i], ub = (&b0.x)[i];
            s0 += fmaxf(__uint_as_float(ua << 16)        + __uint_as_float(ub << 16),        0.f) * w2r[2 * i];
            s0 += fmaxf(__uint_as_float(ua & 0xffff0000u) + __uint_as_float(ub & 0xffff0000u), 0.f) * w2r[2 * i + 1];
            unsigned int uc = (&a1.x)[i], ud = (&b1v.x)[i];
            s1 += fmaxf(__uint_as_float(uc << 16)        + __uint_as_float(ud << 16),        0.f) * w2r[2 * i];
            s1 += fmaxf(__uint_as_float(uc & 0xffff0000u) + __uint_as_float(ud & 0xffff0000u), 0.f) * w2r[2 * i + 1];
        }
        #pragma unroll
        for (int d = 1; d < 16; d <<= 1) {
            s0 += __shfl_xor(s0, d);
            s1 += __shfl_xor(s1, d);
        }
        if (sub == 0) {
            out[e0] = s0 + b2s;
            if (h1) out[e1] = s1 + b2s;
        }
    }
}

extern "C" void kernel_launch(void* const* d_in, const int* in_sizes, int n_in,
                              void* d_out, int out_size, void* d_ws, size_t ws_size,
                              hipStream_t stream)
{
    const float* z_src = (const float*)d_in[0];
    const float* z_dst = (const float*)d_in[1];
    const int*   eidx  = (const int*)d_in[2];
    const float* W1    = (const float*)d_in[3];
    const float* b1    = (const float*)d_in[4];
    const float* W2    = (const float*)d_in[5];
    const float* b2    = (const float*)d_in[6];
    float*       outp  = (float*)d_out;

    const int Nn = in_sizes[0] / HDIM;    // 100000
    const int E  = in_sizes[2] / 2;       // 2000000

    unsigned short* Abuf = (unsigned short*)d_ws;
    unsigned short* Bbuf = Abuf + (size_t)Nn * HDIM;
    unsigned short* Wt   = Bbuf + (size_t)Nn * HDIM;

    convert_w1<<<128, 256, 0, stream>>>(W1, Wt);

    const int gb = (Nn + 63) / 64;
    node_gemm_mfma<<<2 * gb, 256, 0, stream>>>(z_src, z_dst, Wt, b1, Abuf, Bbuf, Nn, gb);

    edge_decode_bf16<<<8192, 256, 0, stream>>>(Abuf, Bbuf, eidx, W2, b2, outp, E);
}